// Round 2
// baseline (239.788 us; speedup 1.0000x reference)
//
#include <hip/hip_runtime.h>
#include <stdint.h>

typedef unsigned short u16;
typedef unsigned int u32;
typedef __attribute__((ext_vector_type(4))) float f32x4;
typedef __attribute__((ext_vector_type(4))) u32 u32x4;
typedef __attribute__((ext_vector_type(2))) u32 u32x2;
typedef __attribute__((ext_vector_type(8))) short bf16x8;

#define NKEYS 65536
#define DIM 1024
#define BQ 256
#define NCLS 103
#define NCAND 64
#define SROW 40   // padded LDS row stride in u16 (80 B = 5 bank-quads, coprime with 8)

__device__ __forceinline__ u16 f2bf(float x) {
  u32 u = __float_as_uint(x);
  u = u + 0x7FFFu + ((u >> 16) & 1u);
  return (u16)(u >> 16);
}
// packed f32x2 -> bf16x2 via HW instr; s0 -> low half (assumed), s1 -> high.
// Used identically on BOTH A(qb) and B(keys) packing, so even if the convention
// is swapped, the intra-pair k-permutation is the same on both GEMM operands
// and the dot product is unchanged.
__device__ __forceinline__ u32 cvtpk(float lo, float hi) {
  u32 d;
  asm("v_cvt_pk_bf16_f32 %0, %1, %2" : "=v"(d) : "v"(lo), "v"(hi));
  return d;
}

// ---------------- small fp32 GEMM: out[m][n] = sum_k A[m][k]*B[n][k], split-K partials
__global__ __launch_bounds__(256) void gemm_nt_f32(
    const float* __restrict__ A, const float* __restrict__ B,
    float* __restrict__ partial)
{
  __shared__ float sAT[16][68];
  __shared__ float sBT[16][68];
  const int tid = threadIdx.x;
  const int n0 = blockIdx.x * 64;
  const int m0 = blockIdx.y * 64;
  const int kz = blockIdx.z;
  const int r = tid & 63, kq = tid >> 6;
  const int tx = tid & 15, ty = tid >> 4;
  float acc[4][4] = {};
  for (int kb = 0; kb < 256; kb += 16) {
    const int kg = kz * 256 + kb + kq * 4;
    const f32x4 av = *(const f32x4*)(A + (size_t)(m0 + r) * DIM + kg);
    const f32x4 bv = *(const f32x4*)(B + (size_t)(n0 + r) * DIM + kg);
    __syncthreads();
#pragma unroll
    for (int i = 0; i < 4; ++i) {
      sAT[kq * 4 + i][r] = av[i];
      sBT[kq * 4 + i][r] = bv[i];
    }
    __syncthreads();
#pragma unroll
    for (int kk = 0; kk < 16; ++kk) {
      const f32x4 a4 = *(const f32x4*)&sAT[kk][ty * 4];
      const f32x4 b4 = *(const f32x4*)&sBT[kk][tx * 4];
#pragma unroll
      for (int i = 0; i < 4; ++i)
#pragma unroll
        for (int j = 0; j < 4; ++j) acc[i][j] += a4[i] * b4[j];
    }
  }
#pragma unroll
  for (int i = 0; i < 4; ++i) {
    f32x4 ov = {acc[i][0], acc[i][1], acc[i][2], acc[i][3]};
    *(f32x4*)(partial + (size_t)kz * 262144u + (size_t)(m0 + ty * 4 + i) * DIM + n0 + tx * 4) = ov;
  }
}

// ---------------- sum split-K partials + bias + relu (optionally also emit bf16)
__global__ __launch_bounds__(256) void reduce_bias_relu(
    const float* __restrict__ partial, const float* __restrict__ bias,
    float* __restrict__ outf, u16* __restrict__ outb, const int wbf)
{
  const int i4 = blockIdx.x * 256 + threadIdx.x;
  const int e = i4 * 4;
  const int n = e & (DIM - 1);
  f32x4 s = *(const f32x4*)(partial + e);
  s += *(const f32x4*)(partial + 262144u + e);
  s += *(const f32x4*)(partial + 2u * 262144u + e);
  s += *(const f32x4*)(partial + 3u * 262144u + e);
  s += *(const f32x4*)(bias + n);
#pragma unroll
  for (int i = 0; i < 4; ++i) s[i] = fmaxf(s[i], 0.f);
  *(f32x4*)(outf + e) = s;
  if (wbf) {
    u32x2 h = {cvtpk(s[0], s[1]), cvtpk(s[2], s[3])};
    *(u32x2*)(outb + e) = h;
  }
}

// ---------------- big bf16 MFMA GEMM: sim[m][n] = (q[m]. key[n]) / max(||key[n]||,1e-8)
// BM=256 (all queries), BN=128 keys/block, BK=32, 512 threads (8 waves, 4m x 2n of 64x64)
// Reg-staged (fp32->bf16 cvt_pk), LDS rows padded to 80B -> conflict-free ds_read_b128.
__global__ __launch_bounds__(512, 4) void simgemm(
    const float* __restrict__ keys, const u16* __restrict__ qb,
    u16* __restrict__ sim)
{
  __shared__ u16 sA[2][256 * SROW];
  __shared__ u16 sB[2][128 * SROW];
  __shared__ float snorm[128];
  const int tid = threadIdx.x;
  const int n0 = blockIdx.x * 128;

  const int a_r = tid >> 1;
  const int a_h = (tid & 1) * 16;
  const u16* agp = qb + (size_t)a_r * DIM + a_h;
  const int a_ws = a_r * SROW + a_h;

  const int b_r = tid >> 2;
  const int b_q = (tid & 3) * 8;
  const float* bgp = keys + (size_t)(n0 + b_r) * DIM + b_q;
  const int b_ws = b_r * SROW + b_q;

  const int lane = tid & 63, wave = tid >> 6;
  const int wm = (wave >> 1) * 64;
  const int wn = (wave & 1) * 64;
  const int lr = lane & 15;
  const int lk = (lane >> 4) * 8;
  const int l4 = (lane >> 4) * 4;

  float nrm = 0.f;
  f32x4 acc[4][4];
#pragma unroll
  for (int i = 0; i < 4; ++i)
#pragma unroll
    for (int j = 0; j < 4; ++j) acc[i][j] = (f32x4){0.f, 0.f, 0.f, 0.f};

  f32x4 bv0, bv1;
  u32x4 av0, av1;

#define LOAD_STAGE(T) do { \
    bv0 = *(const f32x4*)(bgp + (size_t)(T) * 32); \
    bv1 = *(const f32x4*)(bgp + (size_t)(T) * 32 + 4); \
    av0 = *(const u32x4*)(agp + (size_t)(T) * 32); \
    av1 = *(const u32x4*)(agp + (size_t)(T) * 32 + 8); \
  } while (0)

#define WRITE_STAGE(BUF) do { \
    nrm += bv0[0]*bv0[0] + bv0[1]*bv0[1] + bv0[2]*bv0[2] + bv0[3]*bv0[3]; \
    nrm += bv1[0]*bv1[0] + bv1[1]*bv1[1] + bv1[2]*bv1[2] + bv1[3]*bv1[3]; \
    u32x4 bp; \
    bp.x = cvtpk(bv0[0], bv0[1]); bp.y = cvtpk(bv0[2], bv0[3]); \
    bp.z = cvtpk(bv1[0], bv1[1]); bp.w = cvtpk(bv1[2], bv1[3]); \
    *(u32x4*)&sB[BUF][b_ws] = bp; \
    *(u32x4*)&sA[BUF][a_ws] = av0; \
    *(u32x4*)&sA[BUF][a_ws + 8] = av1; \
  } while (0)

  LOAD_STAGE(0);
  WRITE_STAGE(0);
  __syncthreads();

  for (int t = 0; t < 32; ++t) {
    const int cur = t & 1;
    if (t < 31) LOAD_STAGE(t + 1);
    bf16x8 af[4], bfr[4];
#pragma unroll
    for (int f = 0; f < 4; ++f) {
      af[f]  = *(const bf16x8*)&sA[cur][(wm + f * 16 + lr) * SROW + lk];
      bfr[f] = *(const bf16x8*)&sB[cur][(wn + f * 16 + lr) * SROW + lk];
    }
#pragma unroll
    for (int i = 0; i < 4; ++i)
#pragma unroll
      for (int j = 0; j < 4; ++j)
        acc[i][j] = __builtin_amdgcn_mfma_f32_16x16x32_bf16(af[i], bfr[j], acc[i][j], 0, 0, 0);
    if (t < 31) WRITE_STAGE(cur ^ 1);
    __syncthreads();
  }
#undef LOAD_STAGE
#undef WRITE_STAGE

  nrm += __shfl_xor(nrm, 1);
  nrm += __shfl_xor(nrm, 2);
  if ((tid & 3) == 0) snorm[b_r] = nrm;
  __syncthreads();

#pragma unroll
  for (int j = 0; j < 4; ++j) {
    const int nl = wn + j * 16 + lr;
    const float scl = 1.f / fmaxf(sqrtf(snorm[nl]), 1e-8f);
    const size_t ng = (size_t)(n0 + nl);
#pragma unroll
    for (int i = 0; i < 4; ++i) {
      const int mb = wm + i * 16 + l4;
#pragma unroll
      for (int r = 0; r < 4; ++r) {
        sim[(size_t)(mb + r) * NKEYS + ng] = f2bf(acc[i][j][r] * scl);
      }
    }
  }
}

// ---------------- per-row top-64 candidate selection via binary search on u16 keys (regs)
__global__ __launch_bounds__(512) void topk64(
    const u16* __restrict__ sim, int* __restrict__ cand)
{
  __shared__ int redc[8];
  __shared__ int sc1, sc2;
  __shared__ int clist[NCAND];
  const int tid = threadIdx.x;
  const int m = blockIdx.x;
  const u32x4* row = (const u32x4*)(sim + (size_t)m * NKEYS);

  u32 ku[16][4];
#pragma unroll
  for (int i = 0; i < 16; ++i) {
    const u32x4 v = row[i * 512 + tid];
#pragma unroll
    for (int c = 0; c < 4; ++c) {
      u32 lo = v[c] & 0xFFFFu, hi = v[c] >> 16;
      lo ^= (lo & 0x8000u) ? 0xFFFFu : 0x8000u;
      hi ^= (hi & 0x8000u) ? 0xFFFFu : 0x8000u;
      ku[i][c] = lo | (hi << 16);
    }
  }

  int lo_b = 0, hi_b = 65536;
  while (hi_b - lo_b > 1) {
    const u32 mid = (u32)((lo_b + hi_b) >> 1);
    int c = 0;
#pragma unroll
    for (int i = 0; i < 16; ++i)
#pragma unroll
      for (int k = 0; k < 4; ++k) {
        const u32 x = ku[i][k];
        c += ((x & 0xFFFFu) >= mid) ? 1 : 0;
        c += ((x >> 16) >= mid) ? 1 : 0;
      }
#pragma unroll
    for (int j = 32; j; j >>= 1) c += __shfl_xor(c, j);
    if ((tid & 63) == 0) redc[tid >> 6] = c;
    __syncthreads();
    int tot = 0;
#pragma unroll
    for (int w = 0; w < 8; ++w) tot += redc[w];
    if (tot >= NCAND) lo_b = (int)mid; else hi_b = (int)mid;
    __syncthreads();
  }
  const u32 tau = (u32)lo_b;

  int ch = 0;
#pragma unroll
  for (int i = 0; i < 16; ++i)
#pragma unroll
    for (int k = 0; k < 4; ++k) {
      const u32 x = ku[i][k];
      ch += ((x & 0xFFFFu) > tau) ? 1 : 0;
      ch += ((x >> 16) > tau) ? 1 : 0;
    }
#pragma unroll
  for (int j = 32; j; j >>= 1) ch += __shfl_xor(ch, j);
  if ((tid & 63) == 0) redc[tid >> 6] = ch;
  if (tid == 0) { sc1 = 0; sc2 = 0; }
  __syncthreads();
  int nhi = 0;
#pragma unroll
  for (int w = 0; w < 8; ++w) nhi += redc[w];

#pragma unroll
  for (int i = 0; i < 16; ++i)
#pragma unroll
    for (int k = 0; k < 4; ++k) {
      const int nb = (i * 512 + tid) * 8 + k * 2;
      const u32 x = ku[i][k];
      const u32 l = x & 0xFFFFu, h = x >> 16;
      if (l > tau) { int p = atomicAdd(&sc1, 1); clist[p] = nb; }
      else if (l == tau) { int p = atomicAdd(&sc2, 1); if (nhi + p < NCAND) clist[nhi + p] = nb; }
      if (h > tau) { int p = atomicAdd(&sc1, 1); clist[p] = nb + 1; }
      else if (h == tau) { int p = atomicAdd(&sc2, 1); if (nhi + p < NCAND) clist[nhi + p] = nb + 1; }
    }
  __syncthreads();
  if (tid < NCAND) cand[(size_t)m * NCAND + tid] = clist[tid];
}

// ---------------- exact fp32 rescore of 64 candidates, top-32, softmax attention, LN, merged
__global__ __launch_bounds__(256) void rescore_attn(
    const float* __restrict__ keys, const float* __restrict__ q,
    const float* __restrict__ qt, const int* __restrict__ cand,
    const float* __restrict__ ln_g, const float* __restrict__ ln_b,
    float* __restrict__ merged)
{
  __shared__ float sdq[NCAND], sdqt[NCAND], snr[NCAND];
  __shared__ int scand[NCAND];
  __shared__ int srowi[32];
  __shared__ float sw[32];
  __shared__ float red1[4], red2[4];
  const int tid = threadIdx.x, lane = tid & 63, wave = tid >> 6;
  const int m = blockIdx.x;
  if (tid < NCAND) scand[tid] = cand[(size_t)m * NCAND + tid];

  f32x4 q4[4], qt4[4];
#pragma unroll
  for (int i = 0; i < 4; ++i) {
    q4[i]  = *(const f32x4*)(q  + (size_t)m * DIM + i * 256 + lane * 4);
    qt4[i] = *(const f32x4*)(qt + (size_t)m * DIM + i * 256 + lane * 4);
  }
  __syncthreads();

  for (int ci = 0; ci < 16; ++ci) {
    const int c = wave * 16 + ci;
    const float* kr = keys + (size_t)scand[c] * DIM;
    float dq = 0.f, dt = 0.f, ss = 0.f;
#pragma unroll
    for (int i = 0; i < 4; ++i) {
      const f32x4 kv = *(const f32x4*)(kr + i * 256 + lane * 4);
#pragma unroll
      for (int e = 0; e < 4; ++e) {
        dq += kv[e] * q4[i][e];
        dt += kv[e] * qt4[i][e];
        ss += kv[e] * kv[e];
      }
    }
#pragma unroll
    for (int j = 32; j; j >>= 1) {
      dq += __shfl_xor(dq, j);
      dt += __shfl_xor(dt, j);
      ss += __shfl_xor(ss, j);
    }
    if (lane == 0) { sdq[c] = dq; sdqt[c] = dt; snr[c] = ss; }
  }
  __syncthreads();

  if (wave == 0) {
    float v = sdq[lane] / fmaxf(sqrtf(snr[lane]), 1e-8f);
    int p = lane;
#pragma unroll
    for (int k = 2; k <= 64; k <<= 1)
#pragma unroll
      for (int j = k >> 1; j > 0; j >>= 1) {
        const float ov = __shfl_xor(v, j);
        const int op = __shfl_xor(p, j);
        const bool tl = ((lane & j) == 0) == ((lane & k) == 0);
        const bool take = tl ? (ov > v) : (ov < v);
        if (take) { v = ov; p = op; }
      }
    float sc = (lane < 32) ? sdqt[p] : -3.4e38f;
    float mx = sc;
#pragma unroll
    for (int j = 16; j; j >>= 1) mx = fmaxf(mx, __shfl_xor(mx, j));
    const float e = (lane < 32) ? expf(sc - mx) : 0.f;
    float s = e;
#pragma unroll
    for (int j = 16; j; j >>= 1) s += __shfl_xor(s, j);
    if (lane < 32) { sw[lane] = e / s; srowi[lane] = scand[p]; }
  }
  __syncthreads();

  const int d0 = tid * 4;
  f32x4 at = {0.f, 0.f, 0.f, 0.f};
  for (int j = 0; j < 32; ++j) {
    const float wj = sw[j];
    const f32x4 kv = *(const f32x4*)(keys + (size_t)srowi[j] * DIM + d0);
    at += wj * kv;
  }
  const f32x4 qv = *(const f32x4*)(q + (size_t)m * DIM + d0);
  const f32x4 x = at + qv;
  float s1 = x[0] + x[1] + x[2] + x[3];
#pragma unroll
  for (int j = 32; j; j >>= 1) s1 += __shfl_xor(s1, j);
  if (lane == 0) red1[wave] = s1;
  __syncthreads();
  const float mu = (red1[0] + red1[1] + red1[2] + red1[3]) * (1.f / 1024.f);
  const f32x4 xc = x - mu;
  float s2 = xc[0]*xc[0] + xc[1]*xc[1] + xc[2]*xc[2] + xc[3]*xc[3];
#pragma unroll
  for (int j = 32; j; j >>= 1) s2 += __shfl_xor(s2, j);
  if (lane == 0) red2[wave] = s2;
  __syncthreads();
  const float var = (red2[0] + red2[1] + red2[2] + red2[3]) * (1.f / 1024.f);
  const float rstd = rsqrtf(var + 1e-5f);
  const f32x4 g = *(const f32x4*)(ln_g + d0);
  const f32x4 b = *(const f32x4*)(ln_b + d0);
  const f32x4 ma = xc * rstd * g + b;
  float* mrow = merged + (size_t)m * 2048;
  *(f32x4*)(mrow + d0) = qv;
  *(f32x4*)(mrow + 1024 + d0) = ma;
}

// ---------------- classifier: out[m][c] = merged[m] . W_cls[c] + b_cls[c] (2 rows/block)
__global__ __launch_bounds__(256) void classifier(
    const float* __restrict__ merged, const float* __restrict__ Wc,
    const float* __restrict__ bc, float* __restrict__ out)
{
  const int tid = threadIdx.x, lane = tid & 63, wave = tid >> 6;
  const int m0 = blockIdx.x * 2;
  f32x4 r0[8], r1[8];
#pragma unroll
  for (int i = 0; i < 8; ++i) {
    r0[i] = *(const f32x4*)(merged + (size_t)m0 * 2048 + i * 256 + lane * 4);
    r1[i] = *(const f32x4*)(merged + (size_t)(m0 + 1) * 2048 + i * 256 + lane * 4);
  }
  for (int c = wave; c < NCLS; c += 4) {
    const float* w = Wc + (size_t)c * 2048;
    float a0 = 0.f, a1 = 0.f;
#pragma unroll
    for (int i = 0; i < 8; ++i) {
      const f32x4 wv = *(const f32x4*)(w + i * 256 + lane * 4);
#pragma unroll
      for (int e = 0; e < 4; ++e) { a0 += wv[e] * r0[i][e]; a1 += wv[e] * r1[i][e]; }
    }
#pragma unroll
    for (int j = 32; j; j >>= 1) { a0 += __shfl_xor(a0, j); a1 += __shfl_xor(a1, j); }
    if (lane == 0) {
      out[(size_t)m0 * NCLS + c] = a0 + bc[c];
      out[(size_t)(m0 + 1) * NCLS + c] = a1 + bc[c];
    }
  }
}

extern "C" void kernel_launch(void* const* d_in, const int* in_sizes, int n_in,
                              void* d_out, int out_size, void* d_ws, size_t ws_size,
                              hipStream_t stream)
{
  const float* query = (const float*)d_in[1];
  const float* keys  = (const float*)d_in[2];
  const float* Wenc  = (const float*)d_in[3];
  const float* benc  = (const float*)d_in[4];
  const float* Wd    = (const float*)d_in[5];
  const float* bd    = (const float*)d_in[6];
  const float* lng   = (const float*)d_in[7];
  const float* lnb   = (const float*)d_in[8];
  const float* Wcls  = (const float*)d_in[9];
  const float* bcls  = (const float*)d_in[10];
  float* out = (float*)d_out;
  char* ws = (char*)d_ws;

  // workspace layout (bytes)
  float* q   = (float*)(ws + 0);            // 1 MB
  float* qt  = (float*)(ws + 1048576u);     // 1 MB
  u16*   qb  = (u16*)(ws + 2097152u);       // 0.5 MB
  int*   cnd = (int*)(ws + 2621440u);       // 64 KB
  float* mrg = (float*)(ws + 2686976u);     // 2 MB
  char*  big = ws + 4784128u;               // 32 MB (sim; aliased by 4 MB split-K partials)
  float* par = (float*)big;
  u16*   sim = (u16*)big;

  gemm_nt_f32<<<dim3(16, 4, 4), 256, 0, stream>>>(query, Wenc, par);
  reduce_bias_relu<<<256, 256, 0, stream>>>(par, benc, q, qb, 1);
  gemm_nt_f32<<<dim3(16, 4, 4), 256, 0, stream>>>(q, Wd, par);
  reduce_bias_relu<<<256, 256, 0, stream>>>(par, bd, qt, qb, 0);
  simgemm<<<dim3(512), 512, 0, stream>>>(keys, qb, sim);
  topk64<<<256, 512, 0, stream>>>(sim, cnd);
  rescore_attn<<<256, 256, 0, stream>>>(keys, q, qt, cnd, lng, lnb, mrg);
  classifier<<<128, 256, 0, stream>>>(mrg, Wcls, bcls, out);
}

// Round 3
// 197.707 us; speedup vs baseline: 1.2128x; 1.2128x over previous
//
#include <hip/hip_runtime.h>
#include <stdint.h>

typedef unsigned short u16;
typedef unsigned int u32;
typedef __attribute__((ext_vector_type(2))) float f32x2;
typedef __attribute__((ext_vector_type(4))) float f32x4;
typedef __attribute__((ext_vector_type(4))) u32 u32x4;
typedef __attribute__((ext_vector_type(2))) u32 u32x2;
typedef __attribute__((ext_vector_type(8))) short bf16x8;

#define NKEYS 65536
#define DIM 1024
#define BQ 256
#define NCLS 103
#define NCAND 64
#define SROW 40   // padded LDS row stride in u16 (80 B = 5 bank-quads, coprime with 8)

__device__ __forceinline__ u16 f2bf(float x) {
  u32 u = __float_as_uint(x);
  u = u + 0x7FFFu + ((u >> 16) & 1u);
  return (u16)(u >> 16);
}
// packed f32x2 -> bf16x2; used identically on A and B packing so any intra-pair
// k-permutation cancels in the dot product.
__device__ __forceinline__ u32 cvtpk(float lo, float hi) {
  u32 d;
  asm("v_cvt_pk_bf16_f32 %0, %1, %2" : "=v"(d) : "v"(lo), "v"(hi));
  return d;
}

// ---------------- small fp32 GEMM: out[m][n] = sum_k A[m][k]*B[n][k], split-K partials
__global__ __launch_bounds__(256) void gemm_nt_f32(
    const float* __restrict__ A, const float* __restrict__ B,
    float* __restrict__ partial)
{
  __shared__ float sAT[16][68];
  __shared__ float sBT[16][68];
  const int tid = threadIdx.x;
  const int n0 = blockIdx.x * 64;
  const int m0 = blockIdx.y * 64;
  const int kz = blockIdx.z;
  const int r = tid & 63, kq = tid >> 6;
  const int tx = tid & 15, ty = tid >> 4;
  float acc[4][4] = {};
  for (int kb = 0; kb < 256; kb += 16) {
    const int kg = kz * 256 + kb + kq * 4;
    const f32x4 av = *(const f32x4*)(A + (size_t)(m0 + r) * DIM + kg);
    const f32x4 bv = *(const f32x4*)(B + (size_t)(n0 + r) * DIM + kg);
    __syncthreads();
#pragma unroll
    for (int i = 0; i < 4; ++i) {
      sAT[kq * 4 + i][r] = av[i];
      sBT[kq * 4 + i][r] = bv[i];
    }
    __syncthreads();
#pragma unroll
    for (int kk = 0; kk < 16; ++kk) {
      const f32x4 a4 = *(const f32x4*)&sAT[kk][ty * 4];
      const f32x4 b4 = *(const f32x4*)&sBT[kk][tx * 4];
#pragma unroll
      for (int i = 0; i < 4; ++i)
#pragma unroll
        for (int j = 0; j < 4; ++j) acc[i][j] += a4[i] * b4[j];
    }
  }
#pragma unroll
  for (int i = 0; i < 4; ++i) {
    f32x4 ov = {acc[i][0], acc[i][1], acc[i][2], acc[i][3]};
    *(f32x4*)(partial + (size_t)kz * 262144u + (size_t)(m0 + ty * 4 + i) * DIM + n0 + tx * 4) = ov;
  }
}

// ---------------- sum split-K partials + bias + relu (optionally also emit bf16)
__global__ __launch_bounds__(256) void reduce_bias_relu(
    const float* __restrict__ partial, const float* __restrict__ bias,
    float* __restrict__ outf, u16* __restrict__ outb, const int wbf)
{
  const int i4 = blockIdx.x * 256 + threadIdx.x;
  const int e = i4 * 4;
  const int n = e & (DIM - 1);
  f32x4 s = *(const f32x4*)(partial + e);
  s += *(const f32x4*)(partial + 262144u + e);
  s += *(const f32x4*)(partial + 2u * 262144u + e);
  s += *(const f32x4*)(partial + 3u * 262144u + e);
  s += *(const f32x4*)(bias + n);
#pragma unroll
  for (int i = 0; i < 4; ++i) s[i] = fmaxf(s[i], 0.f);
  *(f32x4*)(outf + e) = s;
  if (wbf) {
    u32x2 h = {cvtpk(s[0], s[1]), cvtpk(s[2], s[3])};
    *(u32x2*)(outb + e) = h;
  }
}

// ---------------- big bf16 MFMA GEMM: sim[m][n] = (q[m]. key[n]) / max(||key[n]||,1e-8)
// BM=256 (all queries -> keys read exactly once), BN=128, BK=32, 512 threads.
// 2-deep register prefetch: loads for tile t+2 issue at top of iter t, so the
// vmcnt wait before ds_write covers loads issued a full iteration earlier.
__global__ __launch_bounds__(512) void simgemm(
    const float* __restrict__ keys, const u16* __restrict__ qb,
    u16* __restrict__ sim)
{
  __shared__ u16 sA[2][256 * SROW];
  __shared__ u16 sB[2][128 * SROW];
  __shared__ float snorm[128];
  const int tid = threadIdx.x;
  const int n0 = blockIdx.x * 128;

  const int a_r = tid >> 1;
  const int a_h = (tid & 1) * 16;
  const u16* agp = qb + (size_t)a_r * DIM + a_h;
  const int a_ws = a_r * SROW + a_h;

  const int b_r = tid >> 2;
  const int b_q = (tid & 3) * 8;
  const float* bgp = keys + (size_t)(n0 + b_r) * DIM + b_q;
  const int b_ws = b_r * SROW + b_q;

  const int lane = tid & 63, wave = tid >> 6;
  const int wm = (wave >> 1) * 64;
  const int wn = (wave & 1) * 64;
  const int lr = lane & 15;
  const int lk = (lane >> 4) * 8;
  const int l4 = (lane >> 4) * 4;

  float nrm = 0.f;
  f32x4 acc[4][4];
#pragma unroll
  for (int i = 0; i < 4; ++i)
#pragma unroll
    for (int j = 0; j < 4; ++j) acc[i][j] = (f32x4){0.f, 0.f, 0.f, 0.f};

  // two named register stage slots (no runtime indexing -> no scratch)
  f32x4 bv0a, bv1a, bv0b, bv1b;
  u32x4 av0a, av1a, av0b, av1b;

#define LOAD_STAGE(B0, B1, A0, A1, T) do { \
    B0 = *(const f32x4*)(bgp + (size_t)(T) * 32); \
    B1 = *(const f32x4*)(bgp + (size_t)(T) * 32 + 4); \
    A0 = *(const u32x4*)(agp + (size_t)(T) * 32); \
    A1 = *(const u32x4*)(agp + (size_t)(T) * 32 + 8); \
  } while (0)

#define WRITE_STAGE(B0, B1, A0, A1, BUF) do { \
    nrm += B0[0]*B0[0] + B0[1]*B0[1] + B0[2]*B0[2] + B0[3]*B0[3]; \
    nrm += B1[0]*B1[0] + B1[1]*B1[1] + B1[2]*B1[2] + B1[3]*B1[3]; \
    u32x4 bp; \
    bp.x = cvtpk(B0[0], B0[1]); bp.y = cvtpk(B0[2], B0[3]); \
    bp.z = cvtpk(B1[0], B1[1]); bp.w = cvtpk(B1[2], B1[3]); \
    *(u32x4*)&sB[BUF][b_ws] = bp; \
    *(u32x4*)&sA[BUF][a_ws] = A0; \
    *(u32x4*)&sA[BUF][a_ws + 8] = A1; \
  } while (0)

#define COMPUTE(BUF) do { \
    bf16x8 af[4], bfr[4]; \
    _Pragma("unroll") \
    for (int f = 0; f < 4; ++f) { \
      af[f]  = *(const bf16x8*)&sA[BUF][(wm + f * 16 + lr) * SROW + lk]; \
      bfr[f] = *(const bf16x8*)&sB[BUF][(wn + f * 16 + lr) * SROW + lk]; \
    } \
    _Pragma("unroll") \
    for (int i = 0; i < 4; ++i) \
      _Pragma("unroll") \
      for (int j = 0; j < 4; ++j) \
        acc[i][j] = __builtin_amdgcn_mfma_f32_16x16x32_bf16(af[i], bfr[j], acc[i][j], 0, 0, 0); \
  } while (0)

  // prologue: tile0 -> slot a -> LDS0; tile1 -> slot b (in flight)
  LOAD_STAGE(bv0a, bv1a, av0a, av1a, 0);
  WRITE_STAGE(bv0a, bv1a, av0a, av1a, 0);
  LOAD_STAGE(bv0b, bv1b, av0b, av1b, 1);
  __syncthreads();

  for (int tt = 0; tt < 32; tt += 2) {
    // iter t = tt (even), compute LDS0
    if (tt + 2 < 32) LOAD_STAGE(bv0a, bv1a, av0a, av1a, tt + 2);
    COMPUTE(0);
    WRITE_STAGE(bv0b, bv1b, av0b, av1b, 1);   // tile tt+1 -> LDS1
    __syncthreads();
    // iter t = tt+1 (odd), compute LDS1
    if (tt + 3 < 32) LOAD_STAGE(bv0b, bv1b, av0b, av1b, tt + 3);
    COMPUTE(1);
    if (tt + 2 < 32) WRITE_STAGE(bv0a, bv1a, av0a, av1a, 0);  // tile tt+2 -> LDS0
    __syncthreads();
  }
#undef LOAD_STAGE
#undef WRITE_STAGE
#undef COMPUTE

  nrm += __shfl_xor(nrm, 1);
  nrm += __shfl_xor(nrm, 2);
  if ((tid & 3) == 0) snorm[b_r] = nrm;
  __syncthreads();

#pragma unroll
  for (int j = 0; j < 4; ++j) {
    const int nl = wn + j * 16 + lr;
    const float scl = 1.f / fmaxf(sqrtf(snorm[nl]), 1e-8f);
    const size_t ng = (size_t)(n0 + nl);
#pragma unroll
    for (int i = 0; i < 4; ++i) {
      const int mb = wm + i * 16 + l4;
#pragma unroll
      for (int r = 0; r < 4; ++r) {
        sim[(size_t)(mb + r) * NKEYS + ng] = f2bf(acc[i][j][r] * scl);
      }
    }
  }
}

// ---------------- fused: top-64 select + exact fp32 rescore + top-32 + softmax
// attention + LayerNorm + classifier. One block per query row, 512 threads.
__global__ __launch_bounds__(512) void select_attn_cls(
    const u16* __restrict__ sim, const float* __restrict__ keys,
    const float* __restrict__ q, const float* __restrict__ qt,
    const float* __restrict__ ln_g, const float* __restrict__ ln_b,
    const float* __restrict__ Wc, const float* __restrict__ bc,
    float* __restrict__ out)
{
  __shared__ int redc[8];
  __shared__ int sc1, sc2;
  __shared__ int clist[NCAND];
  __shared__ float sdq[NCAND], sdqt[NCAND], snr[NCAND];
  __shared__ int srowi[32];
  __shared__ float sw[32];
  __shared__ float red1[8], red2[8];
  __shared__ float smg[2048];
  const int tid = threadIdx.x, lane = tid & 63, wave = tid >> 6;
  const int m = blockIdx.x;

  // ---- phase A: top-64 candidates via binary search on monotonic u16 keys
  const u32x4* row = (const u32x4*)(sim + (size_t)m * NKEYS);
  u32 ku[16][4];
#pragma unroll
  for (int i = 0; i < 16; ++i) {
    const u32x4 v = row[i * 512 + tid];
#pragma unroll
    for (int c = 0; c < 4; ++c) {
      u32 lo = v[c] & 0xFFFFu, hi = v[c] >> 16;
      lo ^= (lo & 0x8000u) ? 0xFFFFu : 0x8000u;
      hi ^= (hi & 0x8000u) ? 0xFFFFu : 0x8000u;
      ku[i][c] = lo | (hi << 16);
    }
  }
  int lo_b = 0, hi_b = 65536;
  while (hi_b - lo_b > 1) {
    const u32 mid = (u32)((lo_b + hi_b) >> 1);
    int c = 0;
#pragma unroll
    for (int i = 0; i < 16; ++i)
#pragma unroll
      for (int k = 0; k < 4; ++k) {
        const u32 x = ku[i][k];
        c += ((x & 0xFFFFu) >= mid) ? 1 : 0;
        c += ((x >> 16) >= mid) ? 1 : 0;
      }
#pragma unroll
    for (int j = 32; j; j >>= 1) c += __shfl_xor(c, j);
    if ((tid & 63) == 0) redc[tid >> 6] = c;
    __syncthreads();
    int tot = 0;
#pragma unroll
    for (int w = 0; w < 8; ++w) tot += redc[w];
    if (tot >= NCAND) lo_b = (int)mid; else hi_b = (int)mid;
    __syncthreads();
  }
  const u32 tau = (u32)lo_b;

  int ch = 0;
#pragma unroll
  for (int i = 0; i < 16; ++i)
#pragma unroll
    for (int k = 0; k < 4; ++k) {
      const u32 x = ku[i][k];
      ch += ((x & 0xFFFFu) > tau) ? 1 : 0;
      ch += ((x >> 16) > tau) ? 1 : 0;
    }
#pragma unroll
  for (int j = 32; j; j >>= 1) ch += __shfl_xor(ch, j);
  if ((tid & 63) == 0) redc[tid >> 6] = ch;
  if (tid == 0) { sc1 = 0; sc2 = 0; }
  __syncthreads();
  int nhi = 0;
#pragma unroll
  for (int w = 0; w < 8; ++w) nhi += redc[w];

#pragma unroll
  for (int i = 0; i < 16; ++i)
#pragma unroll
    for (int k = 0; k < 4; ++k) {
      const int nb = (i * 512 + tid) * 8 + k * 2;
      const u32 x = ku[i][k];
      const u32 l = x & 0xFFFFu, h = x >> 16;
      if (l > tau) { int p = atomicAdd(&sc1, 1); clist[p] = nb; }
      else if (l == tau) { int p = atomicAdd(&sc2, 1); if (nhi + p < NCAND) clist[nhi + p] = nb; }
      if (h > tau) { int p = atomicAdd(&sc1, 1); clist[p] = nb + 1; }
      else if (h == tau) { int p = atomicAdd(&sc2, 1); if (nhi + p < NCAND) clist[nhi + p] = nb + 1; }
    }
  __syncthreads();

  // ---- phase B: exact fp32 rescore of 64 candidates (8 per wave)
  f32x4 q4[4], qt4[4];
#pragma unroll
  for (int i = 0; i < 4; ++i) {
    q4[i]  = *(const f32x4*)(q  + (size_t)m * DIM + i * 256 + lane * 4);
    qt4[i] = *(const f32x4*)(qt + (size_t)m * DIM + i * 256 + lane * 4);
  }
  for (int ci = 0; ci < 8; ++ci) {
    const int c = wave * 8 + ci;
    const float* kr = keys + (size_t)clist[c] * DIM;
    float dq = 0.f, dt = 0.f, ss = 0.f;
#pragma unroll
    for (int i = 0; i < 4; ++i) {
      const f32x4 kv = *(const f32x4*)(kr + i * 256 + lane * 4);
#pragma unroll
      for (int e = 0; e < 4; ++e) {
        dq += kv[e] * q4[i][e];
        dt += kv[e] * qt4[i][e];
        ss += kv[e] * kv[e];
      }
    }
#pragma unroll
    for (int j = 32; j; j >>= 1) {
      dq += __shfl_xor(dq, j);
      dt += __shfl_xor(dt, j);
      ss += __shfl_xor(ss, j);
    }
    if (lane == 0) { sdq[c] = dq; sdqt[c] = dt; snr[c] = ss; }
  }
  __syncthreads();

  // ---- phase C: top-32 of 64 (bitonic on wave 0) + softmax weights
  if (wave == 0) {
    float v = sdq[lane] / fmaxf(sqrtf(snr[lane]), 1e-8f);
    int p = lane;
#pragma unroll
    for (int k = 2; k <= 64; k <<= 1)
#pragma unroll
      for (int j = k >> 1; j > 0; j >>= 1) {
        const float ov = __shfl_xor(v, j);
        const int op = __shfl_xor(p, j);
        const bool tl = ((lane & j) == 0) == ((lane & k) == 0);
        const bool take = tl ? (ov > v) : (ov < v);
        if (take) { v = ov; p = op; }
      }
    float sc = (lane < 32) ? sdqt[p] : -3.4e38f;
    float mx = sc;
#pragma unroll
    for (int j = 16; j; j >>= 1) mx = fmaxf(mx, __shfl_xor(mx, j));
    const float e = (lane < 32) ? expf(sc - mx) : 0.f;
    float s = e;
#pragma unroll
    for (int j = 16; j; j >>= 1) s += __shfl_xor(s, j);
    if (lane < 32) { sw[lane] = e / s; srowi[lane] = clist[p]; }
  }
  __syncthreads();

  // ---- phase D: attention + residual + LayerNorm (512 thr x f32x2)
  const int d0 = tid * 2;
  f32x2 at = {0.f, 0.f};
  for (int j = 0; j < 32; ++j) {
    const float wj = sw[j];
    const f32x2 kv = *(const f32x2*)(keys + (size_t)srowi[j] * DIM + d0);
    at += wj * kv;
  }
  const f32x2 qv = *(const f32x2*)(q + (size_t)m * DIM + d0);
  const f32x2 x = at + qv;
  float s1 = x[0] + x[1];
#pragma unroll
  for (int j = 32; j; j >>= 1) s1 += __shfl_xor(s1, j);
  if (lane == 0) red1[wave] = s1;
  __syncthreads();
  float mu = 0.f;
#pragma unroll
  for (int w = 0; w < 8; ++w) mu += red1[w];
  mu *= (1.f / 1024.f);
  const f32x2 xc = x - mu;
  float s2 = xc[0] * xc[0] + xc[1] * xc[1];
#pragma unroll
  for (int j = 32; j; j >>= 1) s2 += __shfl_xor(s2, j);
  if (lane == 0) red2[wave] = s2;
  __syncthreads();
  float var = 0.f;
#pragma unroll
  for (int w = 0; w < 8; ++w) var += red2[w];
  var *= (1.f / 1024.f);
  const float rstd = rsqrtf(var + 1e-5f);
  const f32x2 g = *(const f32x2*)(ln_g + d0);
  const f32x2 b = *(const f32x2*)(ln_b + d0);
  const f32x2 ma = xc * rstd * g + b;
  *(f32x2*)&smg[d0] = qv;
  *(f32x2*)&smg[1024 + d0] = ma;
  __syncthreads();

  // ---- phase E: classifier row (merged in LDS, Wc streamed from L2)
  for (int c = wave; c < NCLS; c += 8) {
    const float* w = Wc + (size_t)c * 2048;
    float a = 0.f;
#pragma unroll
    for (int i = 0; i < 8; ++i) {
      const f32x4 wv = *(const f32x4*)(w + i * 256 + lane * 4);
      const f32x4 mv = *(const f32x4*)&smg[i * 256 + lane * 4];
#pragma unroll
      for (int e = 0; e < 4; ++e) a += wv[e] * mv[e];
    }
#pragma unroll
    for (int j = 32; j; j >>= 1) a += __shfl_xor(a, j);
    if (lane == 0) out[(size_t)m * NCLS + c] = a + bc[c];
  }
}

extern "C" void kernel_launch(void* const* d_in, const int* in_sizes, int n_in,
                              void* d_out, int out_size, void* d_ws, size_t ws_size,
                              hipStream_t stream)
{
  const float* query = (const float*)d_in[1];
  const float* keys  = (const float*)d_in[2];
  const float* Wenc  = (const float*)d_in[3];
  const float* benc  = (const float*)d_in[4];
  const float* Wd    = (const float*)d_in[5];
  const float* bd    = (const float*)d_in[6];
  const float* lng   = (const float*)d_in[7];
  const float* lnb   = (const float*)d_in[8];
  const float* Wcls  = (const float*)d_in[9];
  const float* bcls  = (const float*)d_in[10];
  float* out = (float*)d_out;
  char* ws = (char*)d_ws;

  // workspace layout (bytes)
  float* q   = (float*)(ws + 0);            // 1 MB
  float* qt  = (float*)(ws + 1048576u);     // 1 MB
  u16*   qb  = (u16*)(ws + 2097152u);       // 0.5 MB
  char*  big = ws + 2621440u;               // 32 MB sim (aliased by 4 MB split-K partials)
  float* par = (float*)big;
  u16*   sim = (u16*)big;

  gemm_nt_f32<<<dim3(16, 4, 4), 256, 0, stream>>>(query, Wenc, par);
  reduce_bias_relu<<<256, 256, 0, stream>>>(par, benc, q, qb, 1);
  gemm_nt_f32<<<dim3(16, 4, 4), 256, 0, stream>>>(q, Wd, par);
  reduce_bias_relu<<<256, 256, 0, stream>>>(par, bd, qt, qb, 0);
  simgemm<<<dim3(512), 512, 0, stream>>>(keys, qb, sim);
  select_attn_cls<<<256, 512, 0, stream>>>(sim, keys, q, qt, lng, lnb, Wcls, bcls, out);
}

// Round 4
// 183.462 us; speedup vs baseline: 1.3070x; 1.0776x over previous
//
#include <hip/hip_runtime.h>
#include <stdint.h>

typedef unsigned short u16;
typedef unsigned int u32;
typedef __attribute__((ext_vector_type(2))) float f32x2;
typedef __attribute__((ext_vector_type(4))) float f32x4;
typedef __attribute__((ext_vector_type(4))) u32 u32x4;
typedef __attribute__((ext_vector_type(2))) u32 u32x2;
typedef __attribute__((ext_vector_type(8))) short bf16x8;

#define NKEYS 65536
#define DIM 1024
#define BQ 256
#define NCLS 103
#define NCAND 64
#define SROW 40   // padded LDS row stride in u16 (80 B = 5 bank-quads, coprime with 8)

__device__ __forceinline__ u16 f2bf(float x) {
  u32 u = __float_as_uint(x);
  u = u + 0x7FFFu + ((u >> 16) & 1u);
  return (u16)(u >> 16);
}
// packed f32x2 -> bf16x2; used identically on A and B packing so any intra-pair
// k-permutation cancels in the dot product.
__device__ __forceinline__ u32 cvtpk(float lo, float hi) {
  u32 d;
  asm("v_cvt_pk_bf16_f32 %0, %1, %2" : "=v"(d) : "v"(lo), "v"(hi));
  return d;
}

// ---------------- small fp32 GEMM: out[m][n] = sum_k A[m][k]*B[n][k], split-K partials
// Double-buffered LDS: next k-slice loads while current computes.
__global__ __launch_bounds__(256) void gemm_nt_f32(
    const float* __restrict__ A, const float* __restrict__ B,
    float* __restrict__ partial)
{
  __shared__ float sAT[2][16][68];
  __shared__ float sBT[2][16][68];
  const int tid = threadIdx.x;
  const int n0 = blockIdx.x * 64;
  const int m0 = blockIdx.y * 64;
  const int kz = blockIdx.z;
  const int r = tid & 63, kq = tid >> 6;
  const int tx = tid & 15, ty = tid >> 4;
  float acc[4][4] = {};

  const float* ag = A + (size_t)(m0 + r) * DIM + kz * 256 + kq * 4;
  const float* bg = B + (size_t)(n0 + r) * DIM + kz * 256 + kq * 4;

  f32x4 av = *(const f32x4*)(ag);
  f32x4 bv = *(const f32x4*)(bg);
#pragma unroll
  for (int i = 0; i < 4; ++i) {
    sAT[0][kq * 4 + i][r] = av[i];
    sBT[0][kq * 4 + i][r] = bv[i];
  }
  __syncthreads();

  for (int kb = 0; kb < 16; ++kb) {
    const int cur = kb & 1;
    if (kb + 1 < 16) {
      av = *(const f32x4*)(ag + (kb + 1) * 16);
      bv = *(const f32x4*)(bg + (kb + 1) * 16);
    }
#pragma unroll
    for (int kk = 0; kk < 16; ++kk) {
      const f32x4 a4 = *(const f32x4*)&sAT[cur][kk][ty * 4];
      const f32x4 b4 = *(const f32x4*)&sBT[cur][kk][tx * 4];
#pragma unroll
      for (int i = 0; i < 4; ++i)
#pragma unroll
        for (int j = 0; j < 4; ++j) acc[i][j] += a4[i] * b4[j];
    }
    if (kb + 1 < 16) {
#pragma unroll
      for (int i = 0; i < 4; ++i) {
        sAT[cur ^ 1][kq * 4 + i][r] = av[i];
        sBT[cur ^ 1][kq * 4 + i][r] = bv[i];
      }
    }
    __syncthreads();
  }
#pragma unroll
  for (int i = 0; i < 4; ++i) {
    f32x4 ov = {acc[i][0], acc[i][1], acc[i][2], acc[i][3]};
    *(f32x4*)(partial + (size_t)kz * 262144u + (size_t)(m0 + ty * 4 + i) * DIM + n0 + tx * 4) = ov;
  }
}

// ---------------- sum split-K partials + bias + relu (optionally also emit bf16)
__global__ __launch_bounds__(256) void reduce_bias_relu(
    const float* __restrict__ partial, const float* __restrict__ bias,
    float* __restrict__ outf, u16* __restrict__ outb, const int wbf)
{
  const int i4 = blockIdx.x * 256 + threadIdx.x;
  const int e = i4 * 4;
  const int n = e & (DIM - 1);
  f32x4 s = *(const f32x4*)(partial + e);
  s += *(const f32x4*)(partial + 262144u + e);
  s += *(const f32x4*)(partial + 2u * 262144u + e);
  s += *(const f32x4*)(partial + 3u * 262144u + e);
  s += *(const f32x4*)(bias + n);
#pragma unroll
  for (int i = 0; i < 4; ++i) s[i] = fmaxf(s[i], 0.f);
  *(f32x4*)(outf + e) = s;
  if (wbf) {
    u32x2 h = {cvtpk(s[0], s[1]), cvtpk(s[2], s[3])};
    *(u32x2*)(outb + e) = h;
  }
}

// ---------------- big bf16 MFMA GEMM: sim[m][n] = (q[m]. key[n]) / max(||key[n]||,1e-8)
// BM=256 (keys read exactly once), BN=128, BK=32, 512 threads.
// 4-deep B-side register prefetch (HBM), 2-deep A-side (L2-hot qb).
// Loop unrolled x4 so all slot indices are compile-time (no scratch).
__global__ __launch_bounds__(512) void simgemm(
    const float* __restrict__ keys, const u16* __restrict__ qb,
    u16* __restrict__ sim)
{
  __shared__ u16 sA[2][256 * SROW];
  __shared__ u16 sB[2][128 * SROW];
  __shared__ float snorm[128];
  const int tid = threadIdx.x;
  const int n0 = blockIdx.x * 128;

  const int a_r = tid >> 1;
  const int a_h = (tid & 1) * 16;
  const u16* agp = qb + (size_t)a_r * DIM + a_h;
  const int a_ws = a_r * SROW + a_h;

  const int b_r = tid >> 2;
  const int b_q = (tid & 3) * 8;
  const float* bgp = keys + (size_t)(n0 + b_r) * DIM + b_q;
  const int b_ws = b_r * SROW + b_q;

  const int lane = tid & 63, wave = tid >> 6;
  const int wm = (wave >> 1) * 64;
  const int wn = (wave & 1) * 64;
  const int lr = lane & 15;
  const int lk = (lane >> 4) * 8;
  const int l4 = (lane >> 4) * 4;

  float nrm = 0.f;
  f32x4 acc[4][4];
#pragma unroll
  for (int i = 0; i < 4; ++i)
#pragma unroll
    for (int j = 0; j < 4; ++j) acc[i][j] = (f32x4){0.f, 0.f, 0.f, 0.f};

  // named register stage slots: B depth-4, A depth-2
  f32x4 b00, b01, b10, b11, b20, b21, b30, b31;
  u32x4 a00, a01, a10, a11;

#define LOADB(B0, B1, T) do { \
    B0 = *(const f32x4*)(bgp + (size_t)(T) * 32); \
    B1 = *(const f32x4*)(bgp + (size_t)(T) * 32 + 4); \
  } while (0)
#define LOADA(A0, A1, T) do { \
    A0 = *(const u32x4*)(agp + (size_t)(T) * 32); \
    A1 = *(const u32x4*)(agp + (size_t)(T) * 32 + 8); \
  } while (0)
#define WRITE(B0, B1, A0, A1, BUF) do { \
    nrm += B0[0]*B0[0] + B0[1]*B0[1] + B0[2]*B0[2] + B0[3]*B0[3]; \
    nrm += B1[0]*B1[0] + B1[1]*B1[1] + B1[2]*B1[2] + B1[3]*B1[3]; \
    u32x4 bp; \
    bp.x = cvtpk(B0[0], B0[1]); bp.y = cvtpk(B0[2], B0[3]); \
    bp.z = cvtpk(B1[0], B1[1]); bp.w = cvtpk(B1[2], B1[3]); \
    *(u32x4*)&sB[BUF][b_ws] = bp; \
    *(u32x4*)&sA[BUF][a_ws] = A0; \
    *(u32x4*)&sA[BUF][a_ws + 8] = A1; \
  } while (0)
#define COMPUTE(BUF) do { \
    bf16x8 af[4], bfr[4]; \
    _Pragma("unroll") \
    for (int f = 0; f < 4; ++f) { \
      af[f]  = *(const bf16x8*)&sA[BUF][(wm + f * 16 + lr) * SROW + lk]; \
      bfr[f] = *(const bf16x8*)&sB[BUF][(wn + f * 16 + lr) * SROW + lk]; \
    } \
    _Pragma("unroll") \
    for (int i = 0; i < 4; ++i) \
      _Pragma("unroll") \
      for (int j = 0; j < 4; ++j) \
        acc[i][j] = __builtin_amdgcn_mfma_f32_16x16x32_bf16(af[i], bfr[j], acc[i][j], 0, 0, 0); \
  } while (0)

  // prologue: B tiles 0-3 in flight, A tiles 0-1; tile 0 -> LDS0
  LOADB(b00, b01, 0); LOADB(b10, b11, 1); LOADB(b20, b21, 2); LOADB(b30, b31, 3);
  LOADA(a00, a01, 0); LOADA(a10, a11, 1);
  WRITE(b00, b01, a00, a01, 0);
  __syncthreads();

  for (int tt = 0; tt < 32; tt += 4) {
    // half0: compute tile tt (L0)
    if (tt + 4 < 32) LOADB(b00, b01, tt + 4);
    LOADA(a00, a01, tt + 2);                    // tt+2 <= 30 always
    COMPUTE(0);
    WRITE(b10, b11, a10, a11, 1);               // tile tt+1 -> L1
    __syncthreads();
    // half1: compute tile tt+1 (L1)
    if (tt + 5 < 32) LOADB(b10, b11, tt + 5);
    LOADA(a10, a11, tt + 3);                    // tt+3 <= 31 always
    COMPUTE(1);
    WRITE(b20, b21, a00, a01, 0);               // tile tt+2 -> L0
    __syncthreads();
    // half2: compute tile tt+2 (L0)
    if (tt + 6 < 32) LOADB(b20, b21, tt + 6);
    if (tt + 4 < 32) LOADA(a00, a01, tt + 4);
    COMPUTE(0);
    WRITE(b30, b31, a10, a11, 1);               // tile tt+3 -> L1
    __syncthreads();
    // half3: compute tile tt+3 (L1)
    if (tt + 7 < 32) LOADB(b30, b31, tt + 7);
    if (tt + 5 < 32) LOADA(a10, a11, tt + 5);
    COMPUTE(1);
    if (tt + 4 < 32) WRITE(b00, b01, a00, a01, 0);  // tile tt+4 -> L0
    __syncthreads();
  }
#undef LOADB
#undef LOADA
#undef WRITE
#undef COMPUTE

  nrm += __shfl_xor(nrm, 1);
  nrm += __shfl_xor(nrm, 2);
  if ((tid & 3) == 0) snorm[b_r] = nrm;
  __syncthreads();

#pragma unroll
  for (int j = 0; j < 4; ++j) {
    const int nl = wn + j * 16 + lr;
    const float scl = 1.f / fmaxf(sqrtf(snorm[nl]), 1e-8f);
    const size_t ng = (size_t)(n0 + nl);
#pragma unroll
    for (int i = 0; i < 4; ++i) {
      const int mb = wm + i * 16 + l4;
#pragma unroll
      for (int r = 0; r < 4; ++r) {
        sim[(size_t)(mb + r) * NKEYS + ng] = f2bf(acc[i][j][r] * scl);
      }
    }
  }
}

// ---------------- fused: top-64 select + exact fp32 rescore + top-32 + softmax
// attention + LayerNorm + classifier. One block per query row, 512 threads.
__global__ __launch_bounds__(512) void select_attn_cls(
    const u16* __restrict__ sim, const float* __restrict__ keys,
    const float* __restrict__ q, const float* __restrict__ qt,
    const float* __restrict__ ln_g, const float* __restrict__ ln_b,
    const float* __restrict__ Wc, const float* __restrict__ bc,
    float* __restrict__ out)
{
  __shared__ int redc[8];
  __shared__ int sc1, sc2;
  __shared__ int clist[NCAND];
  __shared__ float sdq[NCAND], sdqt[NCAND], snr[NCAND];
  __shared__ int srowi[32];
  __shared__ float sw[32];
  __shared__ float red1[8], red2[8];
  __shared__ float smg[2048];
  const int tid = threadIdx.x, lane = tid & 63, wave = tid >> 6;
  const int m = blockIdx.x;

  // ---- phase A: top-64 candidates via binary search on monotonic u16 keys
  const u32x4* row = (const u32x4*)(sim + (size_t)m * NKEYS);
  u32 ku[16][4];
#pragma unroll
  for (int i = 0; i < 16; ++i) {
    const u32x4 v = row[i * 512 + tid];
#pragma unroll
    for (int c = 0; c < 4; ++c) {
      u32 lo = v[c] & 0xFFFFu, hi = v[c] >> 16;
      lo ^= (lo & 0x8000u) ? 0xFFFFu : 0x8000u;
      hi ^= (hi & 0x8000u) ? 0xFFFFu : 0x8000u;
      ku[i][c] = lo | (hi << 16);
    }
  }
  int lo_b = 0, hi_b = 65536;
  while (hi_b - lo_b > 1) {
    const u32 mid = (u32)((lo_b + hi_b) >> 1);
    int c = 0;
#pragma unroll
    for (int i = 0; i < 16; ++i)
#pragma unroll
      for (int k = 0; k < 4; ++k) {
        const u32 x = ku[i][k];
        c += ((x & 0xFFFFu) >= mid) ? 1 : 0;
        c += ((x >> 16) >= mid) ? 1 : 0;
      }
#pragma unroll
    for (int j = 32; j; j >>= 1) c += __shfl_xor(c, j);
    if ((tid & 63) == 0) redc[tid >> 6] = c;
    __syncthreads();
    int tot = 0;
#pragma unroll
    for (int w = 0; w < 8; ++w) tot += redc[w];
    if (tot >= NCAND) lo_b = (int)mid; else hi_b = (int)mid;
    __syncthreads();
  }
  const u32 tau = (u32)lo_b;

  int ch = 0;
#pragma unroll
  for (int i = 0; i < 16; ++i)
#pragma unroll
    for (int k = 0; k < 4; ++k) {
      const u32 x = ku[i][k];
      ch += ((x & 0xFFFFu) > tau) ? 1 : 0;
      ch += ((x >> 16) > tau) ? 1 : 0;
    }
#pragma unroll
  for (int j = 32; j; j >>= 1) ch += __shfl_xor(ch, j);
  if ((tid & 63) == 0) redc[tid >> 6] = ch;
  if (tid == 0) { sc1 = 0; sc2 = 0; }
  __syncthreads();
  int nhi = 0;
#pragma unroll
  for (int w = 0; w < 8; ++w) nhi += redc[w];

#pragma unroll
  for (int i = 0; i < 16; ++i)
#pragma unroll
    for (int k = 0; k < 4; ++k) {
      const int nb = (i * 512 + tid) * 8 + k * 2;
      const u32 x = ku[i][k];
      const u32 l = x & 0xFFFFu, h = x >> 16;
      if (l > tau) { int p = atomicAdd(&sc1, 1); clist[p] = nb; }
      else if (l == tau) { int p = atomicAdd(&sc2, 1); if (nhi + p < NCAND) clist[nhi + p] = nb; }
      if (h > tau) { int p = atomicAdd(&sc1, 1); clist[p] = nb + 1; }
      else if (h == tau) { int p = atomicAdd(&sc2, 1); if (nhi + p < NCAND) clist[nhi + p] = nb + 1; }
    }
  __syncthreads();

  // ---- phase B: exact fp32 rescore of 64 candidates (8 per wave)
  f32x4 q4[4], qt4[4];
#pragma unroll
  for (int i = 0; i < 4; ++i) {
    q4[i]  = *(const f32x4*)(q  + (size_t)m * DIM + i * 256 + lane * 4);
    qt4[i] = *(const f32x4*)(qt + (size_t)m * DIM + i * 256 + lane * 4);
  }
  for (int ci = 0; ci < 8; ++ci) {
    const int c = wave * 8 + ci;
    const float* kr = keys + (size_t)clist[c] * DIM;
    float dq = 0.f, dt = 0.f, ss = 0.f;
#pragma unroll
    for (int i = 0; i < 4; ++i) {
      const f32x4 kv = *(const f32x4*)(kr + i * 256 + lane * 4);
#pragma unroll
      for (int e = 0; e < 4; ++e) {
        dq += kv[e] * q4[i][e];
        dt += kv[e] * qt4[i][e];
        ss += kv[e] * kv[e];
      }
    }
#pragma unroll
    for (int j = 32; j; j >>= 1) {
      dq += __shfl_xor(dq, j);
      dt += __shfl_xor(dt, j);
      ss += __shfl_xor(ss, j);
    }
    if (lane == 0) { sdq[c] = dq; sdqt[c] = dt; snr[c] = ss; }
  }
  __syncthreads();

  // ---- phase C: top-32 of 64 (bitonic on wave 0) + softmax weights
  if (wave == 0) {
    float v = sdq[lane] / fmaxf(sqrtf(snr[lane]), 1e-8f);
    int p = lane;
#pragma unroll
    for (int k = 2; k <= 64; k <<= 1)
#pragma unroll
      for (int j = k >> 1; j > 0; j >>= 1) {
        const float ov = __shfl_xor(v, j);
        const int op = __shfl_xor(p, j);
        const bool tl = ((lane & j) == 0) == ((lane & k) == 0);
        const bool take = tl ? (ov > v) : (ov < v);
        if (take) { v = ov; p = op; }
      }
    float sc = (lane < 32) ? sdqt[p] : -3.4e38f;
    float mx = sc;
#pragma unroll
    for (int j = 16; j; j >>= 1) mx = fmaxf(mx, __shfl_xor(mx, j));
    const float e = (lane < 32) ? expf(sc - mx) : 0.f;
    float s = e;
#pragma unroll
    for (int j = 16; j; j >>= 1) s += __shfl_xor(s, j);
    if (lane < 32) { sw[lane] = e / s; srowi[lane] = clist[p]; }
  }
  __syncthreads();

  // ---- phase D: attention + residual + LayerNorm (512 thr x f32x2)
  const int d0 = tid * 2;
  f32x2 at = {0.f, 0.f};
  for (int j = 0; j < 32; ++j) {
    const float wj = sw[j];
    const f32x2 kv = *(const f32x2*)(keys + (size_t)srowi[j] * DIM + d0);
    at += wj * kv;
  }
  const f32x2 qv = *(const f32x2*)(q + (size_t)m * DIM + d0);
  const f32x2 x = at + qv;
  float s1 = x[0] + x[1];
#pragma unroll
  for (int j = 32; j; j >>= 1) s1 += __shfl_xor(s1, j);
  if (lane == 0) red1[wave] = s1;
  __syncthreads();
  float mu = 0.f;
#pragma unroll
  for (int w = 0; w < 8; ++w) mu += red1[w];
  mu *= (1.f / 1024.f);
  const f32x2 xc = x - mu;
  float s2 = xc[0] * xc[0] + xc[1] * xc[1];
#pragma unroll
  for (int j = 32; j; j >>= 1) s2 += __shfl_xor(s2, j);
  if (lane == 0) red2[wave] = s2;
  __syncthreads();
  float var = 0.f;
#pragma unroll
  for (int w = 0; w < 8; ++w) var += red2[w];
  var *= (1.f / 1024.f);
  const float rstd = rsqrtf(var + 1e-5f);
  const f32x2 g = *(const f32x2*)(ln_g + d0);
  const f32x2 b = *(const f32x2*)(ln_b + d0);
  const f32x2 ma = xc * rstd * g + b;
  *(f32x2*)&smg[d0] = qv;
  *(f32x2*)&smg[1024 + d0] = ma;
  __syncthreads();

  // ---- phase E: classifier row (merged in LDS, Wc streamed from L2)
  for (int c = wave; c < NCLS; c += 8) {
    const float* w = Wc + (size_t)c * 2048;
    float a = 0.f;
#pragma unroll
    for (int i = 0; i < 8; ++i) {
      const f32x4 wv = *(const f32x4*)(w + i * 256 + lane * 4);
      const f32x4 mv = *(const f32x4*)&smg[i * 256 + lane * 4];
#pragma unroll
      for (int e = 0; e < 4; ++e) a += wv[e] * mv[e];
    }
#pragma unroll
    for (int j = 32; j; j >>= 1) a += __shfl_xor(a, j);
    if (lane == 0) out[(size_t)m * NCLS + c] = a + bc[c];
  }
}

extern "C" void kernel_launch(void* const* d_in, const int* in_sizes, int n_in,
                              void* d_out, int out_size, void* d_ws, size_t ws_size,
                              hipStream_t stream)
{
  const float* query = (const float*)d_in[1];
  const float* keys  = (const float*)d_in[2];
  const float* Wenc  = (const float*)d_in[3];
  const float* benc  = (const float*)d_in[4];
  const float* Wd    = (const float*)d_in[5];
  const float* bd    = (const float*)d_in[6];
  const float* lng   = (const float*)d_in[7];
  const float* lnb   = (const float*)d_in[8];
  const float* Wcls  = (const float*)d_in[9];
  const float* bcls  = (const float*)d_in[10];
  float* out = (float*)d_out;
  char* ws = (char*)d_ws;

  // workspace layout (bytes)
  float* q   = (float*)(ws + 0);            // 1 MB
  float* qt  = (float*)(ws + 1048576u);     // 1 MB
  u16*   qb  = (u16*)(ws + 2097152u);       // 0.5 MB
  char*  big = ws + 2621440u;               // 32 MB sim (aliased by 4 MB split-K partials)
  float* par = (float*)big;
  u16*   sim = (u16*)big;

  gemm_nt_f32<<<dim3(16, 4, 4), 256, 0, stream>>>(query, Wenc, par);
  reduce_bias_relu<<<256, 256, 0, stream>>>(par, benc, q, qb, 1);
  gemm_nt_f32<<<dim3(16, 4, 4), 256, 0, stream>>>(q, Wd, par);
  reduce_bias_relu<<<256, 256, 0, stream>>>(par, bd, qt, qb, 0);
  simgemm<<<dim3(512), 512, 0, stream>>>(keys, qb, sim);
  select_attn_cls<<<256, 512, 0, stream>>>(sim, keys, q, qt, lng, lnb, Wcls, bcls, out);
}